// Round 1
// baseline (6861.839 us; speedup 1.0000x reference)
//
#include <hip/hip_runtime.h>
#include <math.h>

// Problem constants
#define B_ 4
#define T_ 2048
#define E_ 1024
#define H_ 16
#define HS_ 64
#define FF_ 4096
#define M_ (B_ * T_)          // 8192 rows
#define QKV3_ (3 * H_ * HS_)  // 3072

// ---------------------------------------------------------------------------
// LayerNorm: one block per row (E=1024), 256 threads, float4 per thread.
// ---------------------------------------------------------------------------
__global__ __launch_bounds__(256) void ln_kernel(const float* __restrict__ x,
                                                 const float* __restrict__ g,
                                                 const float* __restrict__ b,
                                                 float* __restrict__ out) {
    const int row = blockIdx.x;
    const int tid = threadIdx.x;
    const float4* x4 = (const float4*)(x + (size_t)row * E_);
    float4 v = x4[tid];
    float s = v.x + v.y + v.z + v.w;
    float ss = v.x * v.x + v.y * v.y + v.z * v.z + v.w * v.w;
    // wave-64 reduce
    for (int off = 32; off > 0; off >>= 1) {
        s += __shfl_down(s, off);
        ss += __shfl_down(ss, off);
    }
    __shared__ float rs[4], rss[4];
    const int wid = tid >> 6;
    if ((tid & 63) == 0) { rs[wid] = s; rss[wid] = ss; }
    __syncthreads();
    const float tot = rs[0] + rs[1] + rs[2] + rs[3];
    const float tot2 = rss[0] + rss[1] + rss[2] + rss[3];
    const float mean = tot * (1.0f / E_);
    const float var = tot2 * (1.0f / E_) - mean * mean;
    const float rstd = rsqrtf(var + 1e-5f);
    const float4 gv = ((const float4*)g)[tid];
    const float4 bv = ((const float4*)b)[tid];
    float4 o;
    o.x = (v.x - mean) * rstd * gv.x + bv.x;
    o.y = (v.y - mean) * rstd * gv.y + bv.y;
    o.z = (v.z - mean) * rstd * gv.z + bv.z;
    o.w = (v.w - mean) * rstd * gv.w + bv.w;
    ((float4*)(out + (size_t)row * E_))[tid] = o;
}

// ---------------------------------------------------------------------------
// fp32 GEMM: C[M,N] = A[M,K] @ W[K,N] (+bias) (+ReLU) (+residual)
// 128x128 tile, BK=16, 256 threads, 8x8 per thread.
// ---------------------------------------------------------------------------
template <bool BIAS, bool RELU, bool RES>
__global__ __launch_bounds__(256) void gemm_kernel(const float* __restrict__ A,
                                                   const float* __restrict__ W,
                                                   const float* __restrict__ bias,
                                                   const float* __restrict__ res,
                                                   float* __restrict__ C,
                                                   int M, int N, int K) {
    __shared__ float As[16][132];  // [k][m], padded
    __shared__ float Bs[16][132];  // [k][n], padded

    const int tid = threadIdx.x;
    const int ty = tid >> 4;       // 0..15
    const int tx = tid & 15;       // 0..15
    const int rowBase = blockIdx.y * 128;
    const int colBase = blockIdx.x * 128;

    float acc[8][8];
#pragma unroll
    for (int i = 0; i < 8; i++)
#pragma unroll
        for (int j = 0; j < 8; j++) acc[i][j] = 0.0f;

    for (int k0 = 0; k0 < K; k0 += 16) {
        // Load A tile: 128 rows x 16 cols = 512 float4
#pragma unroll
        for (int n = 0; n < 2; n++) {
            const int fi = n * 256 + tid;
            const int r = fi >> 2;       // 0..127
            const int c4 = fi & 3;       // 0..3
            const float4 a = *(const float4*)&A[(size_t)(rowBase + r) * K + k0 + c4 * 4];
            As[c4 * 4 + 0][r] = a.x;
            As[c4 * 4 + 1][r] = a.y;
            As[c4 * 4 + 2][r] = a.z;
            As[c4 * 4 + 3][r] = a.w;
        }
        // Load B tile: 16 rows x 128 cols = 512 float4
#pragma unroll
        for (int n = 0; n < 2; n++) {
            const int fi = n * 256 + tid;
            const int r = fi >> 5;       // 0..15
            const int c4 = fi & 31;      // 0..31
            *(float4*)&Bs[r][c4 * 4] =
                *(const float4*)&W[(size_t)(k0 + r) * N + colBase + c4 * 4];
        }
        __syncthreads();
#pragma unroll
        for (int k = 0; k < 16; k++) {
            float a[8], bb[8];
            *(float4*)&a[0] = *(float4*)&As[k][ty * 8];
            *(float4*)&a[4] = *(float4*)&As[k][ty * 8 + 4];
            *(float4*)&bb[0] = *(float4*)&Bs[k][tx * 8];
            *(float4*)&bb[4] = *(float4*)&Bs[k][tx * 8 + 4];
#pragma unroll
            for (int i = 0; i < 8; i++)
#pragma unroll
                for (int j = 0; j < 8; j++) acc[i][j] += a[i] * bb[j];
        }
        __syncthreads();
    }

    // Epilogue
#pragma unroll
    for (int i = 0; i < 8; i++) {
        const int r = rowBase + ty * 8 + i;
#pragma unroll
        for (int j4 = 0; j4 < 2; j4++) {
            const int c = colBase + tx * 8 + j4 * 4;
            float4 v;
            v.x = acc[i][j4 * 4 + 0];
            v.y = acc[i][j4 * 4 + 1];
            v.z = acc[i][j4 * 4 + 2];
            v.w = acc[i][j4 * 4 + 3];
            if (BIAS) {
                const float4 bv = *(const float4*)&bias[c];
                v.x += bv.x; v.y += bv.y; v.z += bv.z; v.w += bv.w;
            }
            if (RELU) {
                v.x = fmaxf(v.x, 0.0f); v.y = fmaxf(v.y, 0.0f);
                v.z = fmaxf(v.z, 0.0f); v.w = fmaxf(v.w, 0.0f);
            }
            if (RES) {
                const float4 rv = *(const float4*)&res[(size_t)r * N + c];
                v.x += rv.x; v.y += rv.y; v.z += rv.z; v.w += rv.w;
            }
            *(float4*)&C[(size_t)r * N + c] = v;
        }
    }
}

// ---------------------------------------------------------------------------
// Flash-style causal attention, fp32.
// Block: 256 threads = one (b, h, 64-query tile). Online softmax.
// qkv layout: [B*T][3072], q at col h*64, k at 1024+h*64, v at 2048+h*64.
// out layout: [B*T][1024] at col h*64.
// ---------------------------------------------------------------------------
__global__ __launch_bounds__(256) void attn_kernel(const float* __restrict__ qkv,
                                                   float* __restrict__ out) {
    __shared__ float Qs[64][68];
    __shared__ float Ks[64][68];
    __shared__ float Vs[64][68];
    __shared__ float Ps[64][68];

    const int tid = threadIdx.x;
    const int ty = tid >> 4;   // 0..15
    const int tx = tid & 15;   // 0..15
    const int qt = blockIdx.x;           // query tile (0..31)
    const int bh = blockIdx.y;           // 0..63
    const int b = bh >> 4;
    const int h = bh & 15;
    const int q0 = qt * 64;
    const size_t rowStride = QKV3_;
    const size_t baseQ = ((size_t)(b * T_) * rowStride) + h * HS_;
    const size_t baseK = baseQ + H_ * HS_;
    const size_t baseV = baseQ + 2 * H_ * HS_;

    // Load Q tile (scaled by 1/sqrt(HS))
#pragma unroll
    for (int n = 0; n < 4; n++) {
        const int fi = n * 256 + tid;
        const int r = fi >> 4;      // 0..63
        const int c4 = fi & 15;     // 0..15
        float4 q = *(const float4*)&qkv[baseQ + (size_t)(q0 + r) * rowStride + c4 * 4];
        q.x *= 0.125f; q.y *= 0.125f; q.z *= 0.125f; q.w *= 0.125f;
        *(float4*)&Qs[r][c4 * 4] = q;
    }

    // Per-thread state: rows qi = ii*16+ty, cols jj*16+tx (strided mapping)
    float m[4], l[4], O[4][4];
#pragma unroll
    for (int ii = 0; ii < 4; ii++) {
        m[ii] = -INFINITY;
        l[ii] = 0.0f;
#pragma unroll
        for (int jj = 0; jj < 4; jj++) O[ii][jj] = 0.0f;
    }

    for (int kt = 0; kt <= qt; kt++) {
        __syncthreads();  // previous PV done before overwriting K/V
        // Load K and V tiles
#pragma unroll
        for (int n = 0; n < 4; n++) {
            const int fi = n * 256 + tid;
            const int r = fi >> 4;
            const int c4 = fi & 15;
            const size_t trow = (size_t)(kt * 64 + r) * rowStride;
            *(float4*)&Ks[r][c4 * 4] = *(const float4*)&qkv[baseK + trow + c4 * 4];
            *(float4*)&Vs[r][c4 * 4] = *(const float4*)&qkv[baseV + trow + c4 * 4];
        }
        __syncthreads();

        // S = Q @ K^T  (each thread: rows ii*16+ty, cols jj*16+tx)
        float s[4][4];
#pragma unroll
        for (int ii = 0; ii < 4; ii++)
#pragma unroll
            for (int jj = 0; jj < 4; jj++) s[ii][jj] = 0.0f;

        for (int d = 0; d < 64; d += 4) {
            float4 qv[4], kv[4];
#pragma unroll
            for (int ii = 0; ii < 4; ii++) qv[ii] = *(const float4*)&Qs[ii * 16 + ty][d];
#pragma unroll
            for (int jj = 0; jj < 4; jj++) kv[jj] = *(const float4*)&Ks[jj * 16 + tx][d];
#pragma unroll
            for (int ii = 0; ii < 4; ii++)
#pragma unroll
                for (int jj = 0; jj < 4; jj++) {
                    s[ii][jj] += qv[ii].x * kv[jj].x + qv[ii].y * kv[jj].y +
                                 qv[ii].z * kv[jj].z + qv[ii].w * kv[jj].w;
                }
        }

        // Causal mask on the diagonal tile
        if (kt == qt) {
#pragma unroll
            for (int ii = 0; ii < 4; ii++) {
                const int qg = ii * 16 + ty;
#pragma unroll
                for (int jj = 0; jj < 4; jj++) {
                    const int kg = jj * 16 + tx;
                    if (kg > qg) s[ii][jj] = -INFINITY;
                }
            }
        }

        // Online softmax update
#pragma unroll
        for (int ii = 0; ii < 4; ii++) {
            float rm = s[ii][0];
#pragma unroll
            for (int jj = 1; jj < 4; jj++) rm = fmaxf(rm, s[ii][jj]);
            rm = fmaxf(rm, __shfl_xor(rm, 1, 16));
            rm = fmaxf(rm, __shfl_xor(rm, 2, 16));
            rm = fmaxf(rm, __shfl_xor(rm, 4, 16));
            rm = fmaxf(rm, __shfl_xor(rm, 8, 16));
            const float mnew = fmaxf(m[ii], rm);
            float rsum = 0.0f;
#pragma unroll
            for (int jj = 0; jj < 4; jj++) {
                const float p = expf(s[ii][jj] - mnew);
                Ps[ii * 16 + ty][jj * 16 + tx] = p;
                rsum += p;
            }
            rsum += __shfl_xor(rsum, 1, 16);
            rsum += __shfl_xor(rsum, 2, 16);
            rsum += __shfl_xor(rsum, 4, 16);
            rsum += __shfl_xor(rsum, 8, 16);
            const float alpha = expf(m[ii] - mnew);
            l[ii] = l[ii] * alpha + rsum;
            m[ii] = mnew;
#pragma unroll
            for (int jj = 0; jj < 4; jj++) O[ii][jj] *= alpha;
        }
        __syncthreads();  // Ps visible to everyone

        // O += P @ V
        for (int k = 0; k < 64; k += 4) {
            float4 pv[4];
#pragma unroll
            for (int ii = 0; ii < 4; ii++) pv[ii] = *(const float4*)&Ps[ii * 16 + ty][k];
#pragma unroll
            for (int kk = 0; kk < 4; kk++) {
                float vv[4];
#pragma unroll
                for (int jj = 0; jj < 4; jj++) vv[jj] = Vs[k + kk][jj * 16 + tx];
                const float p0 = kk == 0 ? 0.0f : 0.0f;  // (placeholder, unused)
#pragma unroll
                for (int ii = 0; ii < 4; ii++) {
                    const float p = (kk == 0) ? pv[ii].x : (kk == 1) ? pv[ii].y
                                   : (kk == 2) ? pv[ii].z : pv[ii].w;
#pragma unroll
                    for (int jj = 0; jj < 4; jj++) O[ii][jj] += p * vv[jj];
                }
            }
        }
    }

    // Epilogue: out[b*T + q0+qi][h*64 + c] = O / l
    const size_t obase = (size_t)(b * T_ + q0) * E_ + h * HS_;
#pragma unroll
    for (int ii = 0; ii < 4; ii++) {
        const float inv = 1.0f / l[ii];
        const int qi = ii * 16 + ty;
#pragma unroll
        for (int jj = 0; jj < 4; jj++) {
            out[obase + (size_t)qi * E_ + jj * 16 + tx] = O[ii][jj] * inv;
        }
    }
}

// ---------------------------------------------------------------------------
// Launch: LN1 -> QKV GEMM -> attention -> proj(+res) -> LN2 -> FF1 -> FF2(+res)
// Workspace (floats): h/attn @ 0 (8.4M), qkv/ff @ 8388608 (ff needs 33.5M)
// Peak ws = 160 MB.
// ---------------------------------------------------------------------------
extern "C" void kernel_launch(void* const* d_in, const int* in_sizes, int n_in,
                              void* d_out, int out_size, void* d_ws, size_t ws_size,
                              hipStream_t stream) {
    const float* x           = (const float*)d_in[0];
    const float* qkv_w       = (const float*)d_in[1];
    const float* attn_proj_w = (const float*)d_in[2];
    const float* attn_proj_b = (const float*)d_in[3];
    const float* ln1_g       = (const float*)d_in[4];
    const float* ln1_b       = (const float*)d_in[5];
    const float* ln2_g       = (const float*)d_in[6];
    const float* ln2_b       = (const float*)d_in[7];
    const float* ff_w1       = (const float*)d_in[8];
    const float* ff_b1       = (const float*)d_in[9];
    const float* ff_w2       = (const float*)d_in[10];
    const float* ff_b2       = (const float*)d_in[11];
    float* out = (float*)d_out;
    float* ws  = (float*)d_ws;

    float* h       = ws;                      // [8192,1024]
    float* qkvbuf  = ws + (size_t)M_ * E_;    // [8192,3072]
    float* attnbuf = ws;                      // reuse h region: [8192,1024]
    float* ffbuf   = ws + (size_t)M_ * E_;    // reuse qkv region: [8192,4096]

    // 1. h = LN1(x)
    ln_kernel<<<M_, 256, 0, stream>>>(x, ln1_g, ln1_b, h);
    // 2. qkv = h @ qkv_w
    gemm_kernel<false, false, false><<<dim3(QKV3_ / 128, M_ / 128), 256, 0, stream>>>(
        h, qkv_w, nullptr, nullptr, qkvbuf, M_, QKV3_, E_);
    // 3. attn = causal_attention(qkv)
    attn_kernel<<<dim3(T_ / 64, B_ * H_), 256, 0, stream>>>(qkvbuf, attnbuf);
    // 4. x1 = x + attn @ attn_proj_w + attn_proj_b   (into d_out)
    gemm_kernel<true, false, true><<<dim3(E_ / 128, M_ / 128), 256, 0, stream>>>(
        attnbuf, attn_proj_w, attn_proj_b, x, out, M_, E_, E_);
    // 5. h2 = LN2(x1)
    ln_kernel<<<M_, 256, 0, stream>>>(out, ln2_g, ln2_b, h);
    // 6. ff = relu(h2 @ ff_w1 + ff_b1)
    gemm_kernel<true, true, false><<<dim3(FF_ / 128, M_ / 128), 256, 0, stream>>>(
        h, ff_w1, ff_b1, nullptr, ffbuf, M_, FF_, E_);
    // 7. out = x1 + ff @ ff_w2 + ff_b2   (residual read of d_out, in-place)
    gemm_kernel<true, false, true><<<dim3(E_ / 128, M_ / 128), 256, 0, stream>>>(
        ffbuf, ff_w2, ff_b2, out, out, M_, E_, FF_);
}

// Round 2
// 672.453 us; speedup vs baseline: 10.2042x; 10.2042x over previous
//
#include <hip/hip_runtime.h>
#include <math.h>

// Problem constants
#define B_ 4
#define T_ 2048
#define E_ 1024
#define H_ 16
#define HS_ 64
#define FF_ 4096
#define M_ (B_ * T_)          // 8192 rows
#define QKV3_ (3 * H_ * HS_)  // 3072

typedef short bf16x8 __attribute__((ext_vector_type(8)));
typedef float f32x4 __attribute__((ext_vector_type(4)));

// fp32 <-> bf16 (round-to-nearest-even), bit ops only
__device__ __forceinline__ unsigned short f2bf(float f) {
    unsigned int u = __float_as_uint(f);
    return (unsigned short)((u + 0x7fffu + ((u >> 16) & 1u)) >> 16);
}
__device__ __forceinline__ float bf2f(unsigned short h) {
    return __uint_as_float(((unsigned int)h) << 16);
}

// async global->LDS, 16B per lane (wave-uniform LDS base + lane*16)
__device__ __forceinline__ void gload16(const void* g, void* l) {
    __builtin_amdgcn_global_load_lds(
        (const __attribute__((address_space(1))) void*)g,
        (__attribute__((address_space(3))) void*)l, 16, 0, 0);
}

// ---------------------------------------------------------------------------
// Weight transpose + cast: W[K][N] fp32 -> WT[N][K] bf16. 32x32 tiles.
// ---------------------------------------------------------------------------
__global__ __launch_bounds__(256) void wT_bf16(const float* __restrict__ W,
                                               unsigned short* __restrict__ WT,
                                               int K, int N) {
    __shared__ float t[32][33];
    const int n0 = blockIdx.x * 32, k0 = blockIdx.y * 32;
    const int tid = threadIdx.x;
#pragma unroll
    for (int i = 0; i < 4; i++) {
        const int idx = i * 256 + tid;
        const int r = idx >> 5, c = idx & 31;
        t[r][c] = W[(size_t)(k0 + r) * N + n0 + c];
    }
    __syncthreads();
#pragma unroll
    for (int i = 0; i < 4; i++) {
        const int idx = i * 256 + tid;
        const int n = idx >> 5, k = idx & 31;
        WT[(size_t)(n0 + n) * K + k0 + k] = f2bf(t[k][n]);
    }
}

// ---------------------------------------------------------------------------
// LayerNorm fp32 in -> bf16 out. One block per row (E=1024), 256 threads.
// ---------------------------------------------------------------------------
__global__ __launch_bounds__(256) void ln_bf16(const float* __restrict__ x,
                                               const float* __restrict__ g,
                                               const float* __restrict__ b,
                                               unsigned short* __restrict__ out) {
    const int row = blockIdx.x;
    const int tid = threadIdx.x;
    const float4 v = ((const float4*)(x + (size_t)row * E_))[tid];
    float s = v.x + v.y + v.z + v.w;
    float ss = v.x * v.x + v.y * v.y + v.z * v.z + v.w * v.w;
    for (int off = 32; off > 0; off >>= 1) {
        s += __shfl_down(s, off);
        ss += __shfl_down(ss, off);
    }
    __shared__ float rs[4], rss[4];
    const int wid = tid >> 6;
    if ((tid & 63) == 0) { rs[wid] = s; rss[wid] = ss; }
    __syncthreads();
    const float tot = rs[0] + rs[1] + rs[2] + rs[3];
    const float tot2 = rss[0] + rss[1] + rss[2] + rss[3];
    const float mean = tot * (1.0f / E_);
    const float var = tot2 * (1.0f / E_) - mean * mean;
    const float rstd = rsqrtf(var + 1e-5f);
    const float4 gv = ((const float4*)g)[tid];
    const float4 bv = ((const float4*)b)[tid];
    ushort4 o;
    o.x = f2bf((v.x - mean) * rstd * gv.x + bv.x);
    o.y = f2bf((v.y - mean) * rstd * gv.y + bv.y);
    o.z = f2bf((v.z - mean) * rstd * gv.z + bv.z);
    o.w = f2bf((v.w - mean) * rstd * gv.w + bv.w);
    ((ushort4*)(out + (size_t)row * E_))[tid] = o;
}

// ---------------------------------------------------------------------------
// bf16 MFMA GEMM: C[M,N] = A[M,K] @ BT[N,K]^T (+bias)(+relu)(+res)
// m97 structure: 128x128 tile, BK=32, 4 waves (2x2), 16x16x32 MFMA,
// global_load_lds width-16 staging, ds_read_b128 fragments.
// ---------------------------------------------------------------------------
template <bool BIASF, bool RELU, bool RES, bool OUTBF16>
__global__ __launch_bounds__(256) void gemm_bf16(
    const unsigned short* __restrict__ A,    // [M][K] bf16
    const unsigned short* __restrict__ BT,   // [N][K] bf16
    const float* __restrict__ bias,
    const float* __restrict__ res,
    float* __restrict__ Cf,
    unsigned short* __restrict__ Cb,
    int M, int N, int K) {
    __shared__ unsigned short Al[128 * 32];  // 8 KB, linear (gload_lds needs it)
    __shared__ unsigned short Bl[128 * 32];

    const int tid = threadIdx.x;
    const int lane = tid & 63;
    const int w = tid >> 6;
    const int wm = w >> 1, wn = w & 1;
    const int rowBase = blockIdx.y * 128, colBase = blockIdx.x * 128;

    f32x4 acc[4][4];
#pragma unroll
    for (int mt = 0; mt < 4; mt++)
#pragma unroll
        for (int nt = 0; nt < 4; nt++)
#pragma unroll
            for (int r = 0; r < 4; r++) acc[mt][nt][r] = 0.0f;

    const size_t rA = (size_t)rowBase * K;
    const size_t rB = (size_t)colBase * K;
    const int lm = lane & 15;
    const int kgo = (lane >> 4) * 16;  // byte offset of this lane's k-group

    for (int k0 = 0; k0 < K; k0 += 32) {
        // stage A,B tiles: 8 KB each = 8 wave-issues each; 2 per wave per tile
#pragma unroll
        for (int i = 0; i < 2; i++) {
            const int c = (w * 2 + i) * 64 + lane;   // 0..511 chunk id
            const int r = c >> 2, kc = c & 3;
            gload16(A + rA + (size_t)r * K + k0 + kc * 8, (char*)Al + c * 16);
            gload16(BT + rB + (size_t)r * K + k0 + kc * 8, (char*)Bl + c * 16);
        }
        __syncthreads();  // drains vmcnt before LDS reads

        bf16x8 af[4], bfr[4];
#pragma unroll
        for (int mt = 0; mt < 4; mt++)
            af[mt] = *(const bf16x8*)((const char*)Al + (wm * 64 + mt * 16 + lm) * 64 + kgo);
#pragma unroll
        for (int nt = 0; nt < 4; nt++)
            bfr[nt] = *(const bf16x8*)((const char*)Bl + (wn * 64 + nt * 16 + lm) * 64 + kgo);
#pragma unroll
        for (int mt = 0; mt < 4; mt++)
#pragma unroll
            for (int nt = 0; nt < 4; nt++)
                acc[mt][nt] = __builtin_amdgcn_mfma_f32_16x16x32_bf16(
                    af[mt], bfr[nt], acc[mt][nt], 0, 0, 0);
        __syncthreads();  // protect LDS before next stage
    }

    // epilogue: C/D layout col=lane&15, row=(lane>>4)*4+reg  [verified m89]
#pragma unroll
    for (int mt = 0; mt < 4; mt++) {
#pragma unroll
        for (int nt = 0; nt < 4; nt++) {
            const int cg = colBase + wn * 64 + nt * 16 + lm;
#pragma unroll
            for (int r = 0; r < 4; r++) {
                const int rg = rowBase + wm * 64 + mt * 16 + (lane >> 4) * 4 + r;
                float v = acc[mt][nt][r];
                if (BIASF) v += bias[cg];
                if (RELU) v = fmaxf(v, 0.0f);
                if (RES) v += res[(size_t)rg * N + cg];
                if (OUTBF16) Cb[(size_t)rg * N + cg] = f2bf(v);
                else Cf[(size_t)rg * N + cg] = v;
            }
        }
    }
}

// ---------------------------------------------------------------------------
// bf16 MFMA flash attention (causal). Block = 256 thr = 4 waves; wave owns 16
// q-rows; kv-tile = 32. Swapped QK^T: S^T = mfma(K, Q) so each lane holds a
// P-row slice for q = lane&15 -> softmax via 2 shfl_xor, P stays in registers
// and feeds PV's A operand directly (bijection f(kg,j)=kg*4+(j&3)+16*(j>>2),
// same f used for the V fragment).
// qkv bf16 [B*T][3072]: Q at h*64, K at 1024+h*64, V at 2048+h*64.
// out bf16 [B*T][1024] at h*64.
// ---------------------------------------------------------------------------
__global__ __launch_bounds__(256) void attn_mfma(const unsigned short* __restrict__ qkv,
                                                 unsigned short* __restrict__ out) {
    __shared__ unsigned short Ks[32 * 72];  // stride 72 elems = 144 B (pad)
    __shared__ unsigned short Vs[32 * 72];

    const int tid = threadIdx.x;
    const int lane = tid & 63;
    const int w = tid >> 6;
    const int qt = blockIdx.x;   // 0..31
    const int bh = blockIdx.y;   // 0..63
    const int b = bh >> 4, h = bh & 15;
    const int bT = b * T_;
    const int q0w = qt * 64 + w * 16;
    const int lm = lane & 15;
    const int kg = lane >> 4;

    // Q fragments (d-chunks of 32), loaded once from global
    const size_t qoff = (size_t)(bT + q0w + lm) * QKV3_ + h * HS_;
    const bf16x8 qf0 = *(const bf16x8*)(qkv + qoff + kg * 8);
    const bf16x8 qf1 = *(const bf16x8*)(qkv + qoff + 32 + kg * 8);

    f32x4 o[4];
#pragma unroll
    for (int dt = 0; dt < 4; dt++)
#pragma unroll
        for (int r = 0; r < 4; r++) o[dt][r] = 0.0f;
    float mrun = -INFINITY, lrun = 0.0f;

    const int ntiles = 2 * qt + 2;
    for (int kt = 0; kt < ntiles; kt++) {
        const int kvbase = kt * 32;
        __syncthreads();  // prior tile's reads done before overwrite
        {
            const int r = tid >> 3, ch = tid & 7;  // 32 rows x 8 chunks of 8
            const size_t krow = (size_t)(bT + kvbase + r) * QKV3_ + h * HS_ + ch * 8;
            *(bf16x8*)(Ks + r * 72 + ch * 8) = *(const bf16x8*)(qkv + krow + E_);
            *(bf16x8*)(Vs + r * 72 + ch * 8) = *(const bf16x8*)(qkv + krow + 2 * E_);
        }
        __syncthreads();
        if (kvbase > q0w + 15) continue;  // fully masked for this wave (uniform)

        // S^T = K @ Q^T : A = K rows (kv), B = Q rows (q); k-dim = d (2 chunks)
        f32x4 z;
        z[0] = z[1] = z[2] = z[3] = 0.0f;
        const bf16x8 a00 = *(const bf16x8*)(Ks + (lm)*72 + kg * 8);
        const bf16x8 a01 = *(const bf16x8*)(Ks + (lm)*72 + 32 + kg * 8);
        const bf16x8 a10 = *(const bf16x8*)(Ks + (16 + lm) * 72 + kg * 8);
        const bf16x8 a11 = *(const bf16x8*)(Ks + (16 + lm) * 72 + 32 + kg * 8);
        f32x4 s0 = __builtin_amdgcn_mfma_f32_16x16x32_bf16(a00, qf0, z, 0, 0, 0);
        s0 = __builtin_amdgcn_mfma_f32_16x16x32_bf16(a01, qf1, s0, 0, 0, 0);
        f32x4 s1 = __builtin_amdgcn_mfma_f32_16x16x32_bf16(a10, qf0, z, 0, 0, 0);
        s1 = __builtin_amdgcn_mfma_f32_16x16x32_bf16(a11, qf1, s1, 0, 0, 0);

        // scale + causal mask. lane holds S^T[kv=kg*4+r (+16)][q=lm]
        const int qg = q0w + lm;
        float sv[8];
#pragma unroll
        for (int r = 0; r < 4; r++) {
            const int kv0 = kvbase + kg * 4 + r;
            sv[r] = (kv0 <= qg) ? s0[r] * 0.125f : -INFINITY;
            sv[4 + r] = (kv0 + 16 <= qg) ? s1[r] * 0.125f : -INFINITY;
        }
        float mx = sv[0];
#pragma unroll
        for (int j = 1; j < 8; j++) mx = fmaxf(mx, sv[j]);
        mx = fmaxf(mx, __shfl_xor(mx, 16));
        mx = fmaxf(mx, __shfl_xor(mx, 32));
        const float mnew = fmaxf(mrun, mx);
        const float alpha = __expf(mrun - mnew);
        float p[8], ls = 0.0f;
#pragma unroll
        for (int j = 0; j < 8; j++) {
            p[j] = __expf(sv[j] - mnew);
            ls += p[j];
        }
        ls += __shfl_xor(ls, 16);
        ls += __shfl_xor(ls, 32);
        lrun = lrun * alpha + ls;
        mrun = mnew;

        // pack P -> bf16 A-fragment (element j is kv f(kg,j) = index j of sv)
        bf16x8 pa;
#pragma unroll
        for (int j = 0; j < 8; j++) ((unsigned short*)&pa)[j] = f2bf(p[j]);

        // rescale O rows (O row q' = kg*4+r; alpha lives at lane q')
#pragma unroll
        for (int r = 0; r < 4; r++) {
            const float ar = __shfl(alpha, kg * 4 + r);
#pragma unroll
            for (int dt = 0; dt < 4; dt++) o[dt][r] *= ar;
        }

        // PV: O[q][d] += P @ V ; B-frag = V[f(kg,j)][dt*16+lm]
#pragma unroll
        for (int dt = 0; dt < 4; dt++) {
            bf16x8 vf;
#pragma unroll
            for (int j = 0; j < 8; j++) {
                const int kvl = kg * 4 + (j & 3) + 16 * (j >> 2);
                ((unsigned short*)&vf)[j] = Vs[kvl * 72 + dt * 16 + lm];
            }
            o[dt] = __builtin_amdgcn_mfma_f32_16x16x32_bf16(pa, vf, o[dt], 0, 0, 0);
        }
    }

    // epilogue: out row q' = kg*4+r, col d = dt*16+lm
#pragma unroll
    for (int r = 0; r < 4; r++) {
        const float li = 1.0f / __shfl(lrun, kg * 4 + r);
        const size_t rowo = (size_t)(bT + q0w + kg * 4 + r) * E_ + h * HS_;
#pragma unroll
        for (int dt = 0; dt < 4; dt++)
            out[rowo + dt * 16 + lm] = f2bf(o[dt][r] * li);
    }
}

// ---------------------------------------------------------------------------
// Workspace layout (bytes):
//   wqkvT  @ 0         :  6291456  [3072][1024] bf16
//   wprojT @ 6291456   :  2097152  [1024][1024]
//   wff1T  @ 8388608   :  8388608  [4096][1024]
//   wff2T  @ 16777216  :  8388608  [1024][4096]
//   hbuf   @ 25165824  : 16777216  [8192][1024] bf16 (LN1 out, reused for LN2)
//   attnb  @ 41943040  : 16777216  [8192][1024] bf16
//   qkvb   @ 58720256  : 50331648  [8192][3072] bf16 (reused as ff1b 67108864)
//   peak 125829120 B (~120 MB)
// ---------------------------------------------------------------------------
extern "C" void kernel_launch(void* const* d_in, const int* in_sizes, int n_in,
                              void* d_out, int out_size, void* d_ws, size_t ws_size,
                              hipStream_t stream) {
    const float* x           = (const float*)d_in[0];
    const float* qkv_w       = (const float*)d_in[1];
    const float* attn_proj_w = (const float*)d_in[2];
    const float* attn_proj_b = (const float*)d_in[3];
    const float* ln1_g       = (const float*)d_in[4];
    const float* ln1_b       = (const float*)d_in[5];
    const float* ln2_g       = (const float*)d_in[6];
    const float* ln2_b       = (const float*)d_in[7];
    const float* ff_w1       = (const float*)d_in[8];
    const float* ff_b1       = (const float*)d_in[9];
    const float* ff_w2       = (const float*)d_in[10];
    const float* ff_b2       = (const float*)d_in[11];
    float* out = (float*)d_out;
    char* wsb = (char*)d_ws;

    unsigned short* wqkvT  = (unsigned short*)(wsb + 0);
    unsigned short* wprojT = (unsigned short*)(wsb + 6291456);
    unsigned short* wff1T  = (unsigned short*)(wsb + 8388608);
    unsigned short* wff2T  = (unsigned short*)(wsb + 16777216);
    unsigned short* hbuf   = (unsigned short*)(wsb + 25165824);
    unsigned short* attnb  = (unsigned short*)(wsb + 41943040);
    unsigned short* qkvb   = (unsigned short*)(wsb + 58720256);
    unsigned short* ff1b   = qkvb;  // reuse (qkv dead after attention)

    // weight transposes (W[K][N] -> WT[N][K] bf16)
    wT_bf16<<<dim3(QKV3_ / 32, E_ / 32), 256, 0, stream>>>(qkv_w, wqkvT, E_, QKV3_);
    wT_bf16<<<dim3(E_ / 32, E_ / 32), 256, 0, stream>>>(attn_proj_w, wprojT, E_, E_);
    wT_bf16<<<dim3(FF_ / 32, E_ / 32), 256, 0, stream>>>(ff_w1, wff1T, E_, FF_);
    wT_bf16<<<dim3(E_ / 32, FF_ / 32), 256, 0, stream>>>(ff_w2, wff2T, FF_, E_);

    // 1. h = LN1(x) -> bf16
    ln_bf16<<<M_, 256, 0, stream>>>(x, ln1_g, ln1_b, hbuf);
    // 2. qkv = h @ qkv_w -> bf16
    gemm_bf16<false, false, false, true><<<dim3(QKV3_ / 128, M_ / 128), 256, 0, stream>>>(
        hbuf, wqkvT, nullptr, nullptr, nullptr, qkvb, M_, QKV3_, E_);
    // 3. attn = causal_flash(qkv) -> bf16
    attn_mfma<<<dim3(T_ / 64, B_ * H_), 256, 0, stream>>>(qkvb, attnb);
    // 4. x1 = x + attn @ proj_w + proj_b -> d_out (fp32)
    gemm_bf16<true, false, true, false><<<dim3(E_ / 128, M_ / 128), 256, 0, stream>>>(
        attnb, wprojT, attn_proj_b, x, out, nullptr, M_, E_, E_);
    // 5. h2 = LN2(x1) -> bf16
    ln_bf16<<<M_, 256, 0, stream>>>(out, ln2_g, ln2_b, hbuf);
    // 6. ff = relu(h2 @ ff_w1 + b1) -> bf16
    gemm_bf16<true, true, false, true><<<dim3(FF_ / 128, M_ / 128), 256, 0, stream>>>(
        hbuf, wff1T, ff_b1, nullptr, nullptr, ff1b, M_, FF_, E_);
    // 7. out = x1 + ff @ ff_w2 + b2 -> d_out (fp32, in-place residual)
    gemm_bf16<true, false, true, false><<<dim3(E_ / 128, M_ / 128), 256, 0, stream>>>(
        ff1b, wff2T, ff_b2, out, out, nullptr, M_, E_, FF_);
    (void)ws_size; (void)in_sizes; (void)n_in; (void)out_size;
}

// Round 4
// 586.802 us; speedup vs baseline: 11.6936x; 1.1460x over previous
//
#include <hip/hip_runtime.h>
#include <math.h>

// Problem constants
#define B_ 4
#define T_ 2048
#define E_ 1024
#define H_ 16
#define HS_ 64
#define FF_ 4096
#define M_ (B_ * T_)          // 8192 rows
#define QKV3_ (3 * H_ * HS_)  // 3072

typedef short bf16x8 __attribute__((ext_vector_type(8)));
typedef short bf16x4 __attribute__((ext_vector_type(4)));
typedef float f32x4 __attribute__((ext_vector_type(4)));

// fp32 -> bf16 (round-to-nearest-even), bit ops only
__device__ __forceinline__ unsigned short f2bf(float f) {
    unsigned int u = __float_as_uint(f);
    return (unsigned short)((u + 0x7fffu + ((u >> 16) & 1u)) >> 16);
}

// async global->LDS, 16B per lane (wave-uniform LDS base + lane*16)
__device__ __forceinline__ void gload16(const void* g, void* l) {
    __builtin_amdgcn_global_load_lds(
        (const __attribute__((address_space(1))) void*)g,
        (__attribute__((address_space(3))) void*)l, 16, 0, 0);
}

// ---------------------------------------------------------------------------
// Weight transpose + cast: W[K][N] fp32 -> WT[N][K] bf16. 32x32 tiles.
// ---------------------------------------------------------------------------
__global__ __launch_bounds__(256) void wT_bf16(const float* __restrict__ W,
                                               unsigned short* __restrict__ WT,
                                               int K, int N) {
    __shared__ float t[32][33];
    const int n0 = blockIdx.x * 32, k0 = blockIdx.y * 32;
    const int tid = threadIdx.x;
#pragma unroll
    for (int i = 0; i < 4; i++) {
        const int idx = i * 256 + tid;
        const int r = idx >> 5, c = idx & 31;
        t[r][c] = W[(size_t)(k0 + r) * N + n0 + c];
    }
    __syncthreads();
#pragma unroll
    for (int i = 0; i < 4; i++) {
        const int idx = i * 256 + tid;
        const int n = idx >> 5, k = idx & 31;
        WT[(size_t)(n0 + n) * K + k0 + k] = f2bf(t[k][n]);
    }
}

// ---------------------------------------------------------------------------
// LayerNorm fp32 in -> bf16 out. One block per row (E=1024), 256 threads.
// ---------------------------------------------------------------------------
__global__ __launch_bounds__(256) void ln_bf16(const float* __restrict__ x,
                                               const float* __restrict__ g,
                                               const float* __restrict__ b,
                                               unsigned short* __restrict__ out) {
    const int row = blockIdx.x;
    const int tid = threadIdx.x;
    const float4 v = ((const float4*)(x + (size_t)row * E_))[tid];
    float s = v.x + v.y + v.z + v.w;
    float ss = v.x * v.x + v.y * v.y + v.z * v.z + v.w * v.w;
    for (int off = 32; off > 0; off >>= 1) {
        s += __shfl_down(s, off);
        ss += __shfl_down(ss, off);
    }
    __shared__ float rs[4], rss[4];
    const int wid = tid >> 6;
    if ((tid & 63) == 0) { rs[wid] = s; rss[wid] = ss; }
    __syncthreads();
    const float tot = rs[0] + rs[1] + rs[2] + rs[3];
    const float tot2 = rss[0] + rss[1] + rss[2] + rss[3];
    const float mean = tot * (1.0f / E_);
    const float var = tot2 * (1.0f / E_) - mean * mean;
    const float rstd = rsqrtf(var + 1e-5f);
    const float4 gv = ((const float4*)g)[tid];
    const float4 bv = ((const float4*)b)[tid];
    ushort4 o;
    o.x = f2bf((v.x - mean) * rstd * gv.x + bv.x);
    o.y = f2bf((v.y - mean) * rstd * gv.y + bv.y);
    o.z = f2bf((v.z - mean) * rstd * gv.z + bv.z);
    o.w = f2bf((v.w - mean) * rstd * gv.w + bv.w);
    ((ushort4*)(out + (size_t)row * E_))[tid] = o;
}

// ---------------------------------------------------------------------------
// bf16 MFMA GEMM: C[M,N] = A[M,K] @ BT[N,K]^T (+bias)(+relu)(+res)
// 128x128 tile, BK=64, 4 waves (2x2), 16x16x32 MFMA.
// global_load_lds w/ source-side XOR swizzle -> conflict-free ds_read_b128.
// XCD-aware block swizzle (requires gridX*gridY % 8 == 0 -- true for all uses).
// ---------------------------------------------------------------------------
template <bool BIASF, bool RELU, bool RES, bool OUTBF16>
__global__ __launch_bounds__(256) void gemm_bf16(
    const unsigned short* __restrict__ A,    // [M][K] bf16
    const unsigned short* __restrict__ BT,   // [N][K] bf16
    const float* __restrict__ bias,
    const float* __restrict__ res,
    float* __restrict__ Cf,
    unsigned short* __restrict__ Cb,
    int M, int N, int K) {
    __shared__ unsigned short Al[128 * 64];  // 16 KB, linear (gload_lds dest)
    __shared__ unsigned short Bl[128 * 64];

    const int tid = threadIdx.x;
    const int lane = tid & 63;
    const int w = tid >> 6;
    const int wm = w >> 1, wn = w & 1;

    // XCD swizzle: contiguous chunk of blocks per XCD
    const int gx = gridDim.x;
    const int nwg = gx * gridDim.y;
    const int lin = blockIdx.y * gx + blockIdx.x;
    const int cpx = nwg >> 3;
    const int swz = (lin & 7) * cpx + (lin >> 3);
    const int rowBase = (swz / gx) * 128, colBase = (swz % gx) * 128;

    f32x4 acc[4][4];
#pragma unroll
    for (int mt = 0; mt < 4; mt++)
#pragma unroll
        for (int nt = 0; nt < 4; nt++)
#pragma unroll
            for (int r = 0; r < 4; r++) acc[mt][nt][r] = 0.0f;

    const size_t rA = (size_t)rowBase * K;
    const size_t rB = (size_t)colBase * K;
    const int lm = lane & 15;
    const int kg = lane >> 4;

    for (int k0 = 0; k0 < K; k0 += 64) {
        // stage A,B tiles: 128x64 each = 1024 16B-chunks each, 4/thread each.
        // source k-slot pre-swizzled s^=(r&7) so LDS is effectively swizzled.
#pragma unroll
        for (int i = 0; i < 4; i++) {
            const int c = (w * 4 + i) * 64 + lane;
            const int r = c >> 3, s = c & 7;
            const int ss = s ^ (r & 7);
            gload16(A + rA + (size_t)r * K + k0 + ss * 8, (char*)Al + c * 16);
            gload16(BT + rB + (size_t)r * K + k0 + ss * 8, (char*)Bl + c * 16);
        }
        __syncthreads();  // drains vmcnt before LDS reads

#pragma unroll
        for (int ks = 0; ks < 2; ks++) {
            bf16x8 af[4], bfr[4];
#pragma unroll
            for (int mt = 0; mt < 4; mt++)
                af[mt] = *(const bf16x8*)(Al + (wm * 64 + mt * 16 + lm) * 64 +
                                          (((ks * 4 + kg) ^ (lm & 7)) * 8));
#pragma unroll
            for (int nt = 0; nt < 4; nt++)
                bfr[nt] = *(const bf16x8*)(Bl + (wn * 64 + nt * 16 + lm) * 64 +
                                           (((ks * 4 + kg) ^ (lm & 7)) * 8));
#pragma unroll
            for (int mt = 0; mt < 4; mt++)
#pragma unroll
                for (int nt = 0; nt < 4; nt++)
                    acc[mt][nt] = __builtin_amdgcn_mfma_f32_16x16x32_bf16(
                        af[mt], bfr[nt], acc[mt][nt], 0, 0, 0);
        }
        __syncthreads();  // protect LDS before next stage
    }

    // epilogue: C/D layout col=lane&15, row=(lane>>4)*4+reg
#pragma unroll
    for (int mt = 0; mt < 4; mt++) {
#pragma unroll
        for (int nt = 0; nt < 4; nt++) {
            const int cg = colBase + wn * 64 + nt * 16 + lm;
#pragma unroll
            for (int r = 0; r < 4; r++) {
                const int rg = rowBase + wm * 64 + mt * 16 + kg * 4 + r;
                float v = acc[mt][nt][r];
                if (BIASF) v += bias[cg];
                if (RELU) v = fmaxf(v, 0.0f);
                if (RES) v += res[(size_t)rg * N + cg];
                if (OUTBF16) Cb[(size_t)rg * N + cg] = f2bf(v);
                else Cf[(size_t)rg * N + cg] = v;
            }
        }
    }
}

// ---------------------------------------------------------------------------
// bf16 MFMA flash attention v2 (causal).
// Block = 256 thr = 4 waves; wave owns 32 q-rows (2 groups of 16); KVBLK=64.
// Swapped QK^T (S^T = mfma(K,Q)): lane holds P-row slice for q=lane&15.
// K tile: linear [64][64] with XOR swizzle ((row&7) on 16B slot) -> b128 ok.
// V tile: transposed [d][kv] pitch 72, kv-slot XOR-swizzled by d-octet:
//   elem (d,kv) at Vt[d*72 + (kv ^ (((d>>3)&7)<<2))]  -> spreads write banks
//   (without it, chV's bank contribution is 288 = 0 mod 32: 8-way on 8 banks).
// vf = 2x ds_read_b64 (slot bijection f(kg,j)=kg*4+(j&3)+16*(j>>2) contiguous
// in j&3); vf shared by both q-groups.
// Softmax in exp2 domain; defer-max (11.5 lg2 ~ e^8); T14 early staging.
// qt = 15 - blockIdx.x (longest blocks dispatch first).
// ---------------------------------------------------------------------------
__global__ __launch_bounds__(256) void attn_mfma2(const unsigned short* __restrict__ qkv,
                                                  unsigned short* __restrict__ out) {
    __shared__ unsigned short Ks[64 * 64];  // 8 KB, XOR-swizzled
    __shared__ unsigned short Vt[64 * 72];  // 9 KB, [d][kv] pitch 72

    const int tid = threadIdx.x;
    const int lane = tid & 63;
    const int w = tid >> 6;
    const int lm = lane & 15;
    const int kg = lane >> 4;
    const int qt = 15 - blockIdx.x;      // 0..15, descending dispatch
    const int bh = blockIdx.y;           // 0..63
    const int b = bh >> 4, h = bh & 15;
    const int bT = b * T_;
    const int q0w = qt * 128 + w * 32;
    const float K1 = 0.18033688011f;     // 0.125 * log2(e)

    // Q fragments [qg][d-chunk], hoisted
    bf16x8 qf[2][2];
#pragma unroll
    for (int qg = 0; qg < 2; qg++) {
        const size_t qo = (size_t)(bT + q0w + qg * 16 + lm) * QKV3_ + h * HS_;
#pragma unroll
        for (int dc = 0; dc < 2; dc++)
            qf[qg][dc] = *(const bf16x8*)(qkv + qo + dc * 32 + kg * 8);
    }

    f32x4 o[2][4];
#pragma unroll
    for (int qg = 0; qg < 2; qg++)
#pragma unroll
        for (int dt = 0; dt < 4; dt++)
#pragma unroll
            for (int r = 0; r < 4; r++) o[qg][dt][r] = 0.0f;
    float m2[2] = {-INFINITY, -INFINITY};
    float l[2] = {0.0f, 0.0f};

    // staging assignment
    const int rK = tid >> 3, chK = tid & 7;        // K: rows rK, rK+32; chunk chK
    const int sK = (chK ^ (rK & 7)) * 8;           // swizzled LDS slot (elems)
    const int rp = tid >> 3, chV = tid & 7;        // V: row pair 2rp,2rp+1
    const int vws = (2 * rp) ^ (chV << 2);         // kv-slot for V writes

    const size_t hK = E_ + h * HS_;
    const size_t hV = 2 * E_ + h * HS_;
    bf16x8 kA, kB, vA, vB;

#define LOADT(kvb)                                                                          \
    do {                                                                                    \
        kA = *(const bf16x8*)(qkv + (size_t)(bT + (kvb) + rK) * QKV3_ + hK + chK * 8);      \
        kB = *(const bf16x8*)(qkv + (size_t)(bT + (kvb) + rK + 32) * QKV3_ + hK + chK * 8); \
        vA = *(const bf16x8*)(qkv + (size_t)(bT + (kvb) + 2 * rp) * QKV3_ + hV + chV * 8);  \
        vB = *(const bf16x8*)(qkv + (size_t)(bT + (kvb) + 2 * rp + 1) * QKV3_ + hV + chV * 8); \
    } while (0)

    const int nt = 2 * (qt + 1);
    LOADT(0);
    for (int t = 0; t < nt; t++) {
        const int kvbase = t * 64;
        __syncthreads();  // previous tile's LDS reads complete
        // K: 2x b128 swizzled-dest writes
        *(bf16x8*)(Ks + rK * 64 + sK) = kA;
        *(bf16x8*)(Ks + (rK + 32) * 64 + sK) = kB;
        // V: transpose-scatter, 8x b32 (pair of kv rows packed), swizzled slot
#pragma unroll
        for (int i = 0; i < 8; i++) {
            const unsigned int pv = (unsigned int)(unsigned short)vA[i] |
                                    ((unsigned int)(unsigned short)vB[i] << 16);
            *(unsigned int*)(Vt + (chV * 8 + i) * 72 + vws) = pv;
        }
        if (t + 1 < nt) LOADT((t + 1) * 64);  // early-issue next tile (T14)
        __syncthreads();
        if (kvbase > q0w + 31) continue;  // wave fully masked (uniform)

        // K fragments (conflict-free swizzled b128)
        bf16x8 af[4][2];
#pragma unroll
        for (int g = 0; g < 4; g++)
#pragma unroll
            for (int dc = 0; dc < 2; dc++)
                af[g][dc] = *(const bf16x8*)(Ks + (g * 16 + lm) * 64 +
                                             (((dc * 4 + kg) ^ (lm & 7)) * 8));

        bf16x8 pa[2][2];
#pragma unroll
        for (int qg = 0; qg < 2; qg++) {
            f32x4 z = {0.0f, 0.0f, 0.0f, 0.0f};
            f32x4 s[4];
#pragma unroll
            for (int g = 0; g < 4; g++) {
                s[g] = __builtin_amdgcn_mfma_f32_16x16x32_bf16(af[g][0], qf[qg][0], z, 0, 0, 0);
                s[g] = __builtin_amdgcn_mfma_f32_16x16x32_bf16(af[g][1], qf[qg][1], s[g], 0, 0, 0);
            }
            const int qrow = q0w + qg * 16 + lm;
            float sv[16];
#pragma unroll
            for (int g = 0; g < 4; g++)
#pragma unroll
                for (int r = 0; r < 4; r++) sv[g * 4 + r] = s[g][r];
            if (kvbase + 63 > q0w + qg * 16) {  // diagonal tile: apply causal mask
#pragma unroll
                for (int g = 0; g < 4; g++)
#pragma unroll
                    for (int r = 0; r < 4; r++) {
                        const int kv = kvbase + g * 16 + kg * 4 + r;
                        if (kv > qrow) sv[g * 4 + r] = -INFINITY;
                    }
            }
            float mx = sv[0];
#pragma unroll
            for (int j = 1; j < 16; j++) mx = fmaxf(mx, sv[j]);
            mx = fmaxf(mx, __shfl_xor(mx, 16));
            mx = fmaxf(mx, __shfl_xor(mx, 32));
            const float mx2 = mx * K1;
            // defer-max: rescale only when max grew beyond threshold (uniform)
            if (!__all(m2[qg] > -1e30f && mx2 <= m2[qg] + 11.5f)) {
                const float m2new = fmaxf(m2[qg], mx2);
                const float alpha = exp2f(m2[qg] - m2new);
#pragma unroll
                for (int r = 0; r < 4; r++) {
                    const float ar = __shfl(alpha, kg * 4 + r);
#pragma unroll
                    for (int dt = 0; dt < 4; dt++) o[qg][dt][r] *= ar;
                }
                l[qg] *= alpha;
                m2[qg] = m2new;
            }
            float p[16], ls = 0.0f;
#pragma unroll
            for (int j = 0; j < 16; j++) {
                p[j] = exp2f(fmaf(sv[j], K1, -m2[qg]));
                ls += p[j];
            }
            ls += __shfl_xor(ls, 16);
            ls += __shfl_xor(ls, 32);
            l[qg] += ls;
#pragma unroll
            for (int j = 0; j < 8; j++) {
                ((unsigned short*)&pa[qg][0])[j] = f2bf(p[j]);
                ((unsigned short*)&pa[qg][1])[j] = f2bf(p[8 + j]);
            }
        }

        // PV: vf fragments (2x b64 each, unswizzled via row-octet XOR) shared
        // by both q-groups
#pragma unroll
        for (int dt = 0; dt < 4; dt++) {
            const int drow = dt * 16 + lm;
            const unsigned short* vrow = Vt + drow * 72;
            const int xo = (kg * 4) ^ (((drow >> 3) & 7) << 2);
#pragma unroll
            for (int c = 0; c < 2; c++) {
                const bf16x4 lo = *(const bf16x4*)(vrow + c * 32 + xo);
                const bf16x4 hi = *(const bf16x4*)(vrow + c * 32 + (xo ^ 16));
                const bf16x8 vf = __builtin_shufflevector(lo, hi, 0, 1, 2, 3, 4, 5, 6, 7);
                o[0][dt] = __builtin_amdgcn_mfma_f32_16x16x32_bf16(pa[0][c], vf, o[0][dt], 0, 0, 0);
                o[1][dt] = __builtin_amdgcn_mfma_f32_16x16x32_bf16(pa[1][c], vf, o[1][dt], 0, 0, 0);
            }
        }
    }
#undef LOADT

    // epilogue: out row q = kg*4+r (per qg), col d = dt*16+lm
#pragma unroll
    for (int qg = 0; qg < 2; qg++)
#pragma unroll
        for (int r = 0; r < 4; r++) {
            const float li = 1.0f / __shfl(l[qg], kg * 4 + r);
            const size_t ro = (size_t)(bT + q0w + qg * 16 + kg * 4 + r) * E_ + h * HS_;
#pragma unroll
            for (int dt = 0; dt < 4; dt++)
                out[ro + dt * 16 + lm] = f2bf(o[qg][dt][r] * li);
        }
}

// ---------------------------------------------------------------------------
// Workspace layout (bytes): peak ~120 MB.
// ---------------------------------------------------------------------------
extern "C" void kernel_launch(void* const* d_in, const int* in_sizes, int n_in,
                              void* d_out, int out_size, void* d_ws, size_t ws_size,
                              hipStream_t stream) {
    const float* x           = (const float*)d_in[0];
    const float* qkv_w       = (const float*)d_in[1];
    const float* attn_proj_w = (const float*)d_in[2];
    const float* attn_proj_b = (const float*)d_in[3];
    const float* ln1_g       = (const float*)d_in[4];
    const float* ln1_b       = (const float*)d_in[5];
    const float* ln2_g       = (const float*)d_in[6];
    const float* ln2_b       = (const float*)d_in[7];
    const float* ff_w1       = (const float*)d_in[8];
    const float* ff_b1       = (const float*)d_in[9];
    const float* ff_w2       = (const float*)d_in[10];
    const float* ff_b2       = (const float*)d_in[11];
    float* out = (float*)d_out;
    char* wsb = (char*)d_ws;

    unsigned short* wqkvT  = (unsigned short*)(wsb + 0);
    unsigned short* wprojT = (unsigned short*)(wsb + 6291456);
    unsigned short* wff1T  = (unsigned short*)(wsb + 8388608);
    unsigned short* wff2T  = (unsigned short*)(wsb + 16777216);
    unsigned short* hbuf   = (unsigned short*)(wsb + 25165824);
    unsigned short* attnb  = (unsigned short*)(wsb + 41943040);
    unsigned short* qkvb   = (unsigned short*)(wsb + 58720256);
    unsigned short* ff1b   = qkvb;  // reuse (qkv dead after attention)

    // weight transposes (W[K][N] -> WT[N][K] bf16)
    wT_bf16<<<dim3(QKV3_ / 32, E_ / 32), 256, 0, stream>>>(qkv_w, wqkvT, E_, QKV3_);
    wT_bf16<<<dim3(E_ / 32, E_ / 32), 256, 0, stream>>>(attn_proj_w, wprojT, E_, E_);
    wT_bf16<<<dim3(FF_ / 32, E_ / 32), 256, 0, stream>>>(ff_w1, wff1T, E_, FF_);
    wT_bf16<<<dim3(E_ / 32, FF_ / 32), 256, 0, stream>>>(ff_w2, wff2T, FF_, E_);

    // 1. h = LN1(x) -> bf16
    ln_bf16<<<M_, 256, 0, stream>>>(x, ln1_g, ln1_b, hbuf);
    // 2. qkv = h @ qkv_w -> bf16
    gemm_bf16<false, false, false, true><<<dim3(QKV3_ / 128, M_ / 128), 256, 0, stream>>>(
        hbuf, wqkvT, nullptr, nullptr, nullptr, qkvb, M_, QKV3_, E_);
    // 3. attn = causal_flash(qkv) -> bf16
    attn_mfma2<<<dim3(T_ / 128, B_ * H_), 256, 0, stream>>>(qkvb, attnb);
    // 4. x1 = x + attn @ proj_w + proj_b -> d_out (fp32)
    gemm_bf16<true, false, true, false><<<dim3(E_ / 128, M_ / 128), 256, 0, stream>>>(
        attnb, wprojT, attn_proj_b, x, out, nullptr, M_, E_, E_);
    // 5. h2 = LN2(x1) -> bf16
    ln_bf16<<<M_, 256, 0, stream>>>(out, ln2_g, ln2_b, hbuf);
    // 6. ff = relu(h2 @ ff_w1 + b1) -> bf16
    gemm_bf16<true, true, false, true><<<dim3(FF_ / 128, M_ / 128), 256, 0, stream>>>(
        hbuf, wff1T, ff_b1, nullptr, nullptr, ff1b, M_, FF_, E_);
    // 7. out = x1 + ff @ ff_w2 + b2 -> d_out (fp32, in-place residual)
    gemm_bf16<true, false, true, false><<<dim3(E_ / 128, M_ / 128), 256, 0, stream>>>(
        ff1b, wff2T, ff_b2, out, out, nullptr, M_, E_, FF_);
    (void)ws_size; (void)in_sizes; (void)n_in; (void)out_size;
}

// Round 6
// 570.728 us; speedup vs baseline: 12.0230x; 1.0282x over previous
//
#include <hip/hip_runtime.h>
#include <math.h>

// Problem constants
#define B_ 4
#define T_ 2048
#define E_ 1024
#define H_ 16
#define HS_ 64
#define FF_ 4096
#define M_ (B_ * T_)          // 8192 rows
#define QKV3_ (3 * H_ * HS_)  // 3072

typedef short bf16x8 __attribute__((ext_vector_type(8)));
typedef short bf16x4 __attribute__((ext_vector_type(4)));
typedef float f32x4 __attribute__((ext_vector_type(4)));

// fp32 -> bf16 (round-to-nearest-even), bit ops only
__device__ __forceinline__ unsigned short f2bf(float f) {
    unsigned int u = __float_as_uint(f);
    return (unsigned short)((u + 0x7fffu + ((u >> 16) & 1u)) >> 16);
}

// async global->LDS, 16B per lane (wave-uniform LDS base + lane*16)
__device__ __forceinline__ void gload16(const void* g, void* l) {
    __builtin_amdgcn_global_load_lds(
        (const __attribute__((address_space(1))) void*)g,
        (__attribute__((address_space(3))) void*)l, 16, 0, 0);
}

// ---------------------------------------------------------------------------
// Weight transpose + cast: W[K][N] fp32 -> WT[N][K] bf16. 32x32 tiles.
// ---------------------------------------------------------------------------
__global__ __launch_bounds__(256) void wT_bf16(const float* __restrict__ W,
                                               unsigned short* __restrict__ WT,
                                               int K, int N) {
    __shared__ float t[32][33];
    const int n0 = blockIdx.x * 32, k0 = blockIdx.y * 32;
    const int tid = threadIdx.x;
#pragma unroll
    for (int i = 0; i < 4; i++) {
        const int idx = i * 256 + tid;
        const int r = idx >> 5, c = idx & 31;
        t[r][c] = W[(size_t)(k0 + r) * N + n0 + c];
    }
    __syncthreads();
#pragma unroll
    for (int i = 0; i < 4; i++) {
        const int idx = i * 256 + tid;
        const int n = idx >> 5, k = idx & 31;
        WT[(size_t)(n0 + n) * K + k0 + k] = f2bf(t[k][n]);
    }
}

// ---------------------------------------------------------------------------
// LayerNorm fp32 in -> bf16 out. One block per row (E=1024), 256 threads.
// ---------------------------------------------------------------------------
__global__ __launch_bounds__(256) void ln_bf16(const float* __restrict__ x,
                                               const float* __restrict__ g,
                                               const float* __restrict__ b,
                                               unsigned short* __restrict__ out) {
    const int row = blockIdx.x;
    const int tid = threadIdx.x;
    const float4 v = ((const float4*)(x + (size_t)row * E_))[tid];
    float s = v.x + v.y + v.z + v.w;
    float ss = v.x * v.x + v.y * v.y + v.z * v.z + v.w * v.w;
    for (int off = 32; off > 0; off >>= 1) {
        s += __shfl_down(s, off);
        ss += __shfl_down(ss, off);
    }
    __shared__ float rs[4], rss[4];
    const int wid = tid >> 6;
    if ((tid & 63) == 0) { rs[wid] = s; rss[wid] = ss; }
    __syncthreads();
    const float tot = rs[0] + rs[1] + rs[2] + rs[3];
    const float tot2 = rss[0] + rss[1] + rss[2] + rss[3];
    const float mean = tot * (1.0f / E_);
    const float var = tot2 * (1.0f / E_) - mean * mean;
    const float rstd = rsqrtf(var + 1e-5f);
    const float4 gv = ((const float4*)g)[tid];
    const float4 bv = ((const float4*)b)[tid];
    ushort4 o;
    o.x = f2bf((v.x - mean) * rstd * gv.x + bv.x);
    o.y = f2bf((v.y - mean) * rstd * gv.y + bv.y);
    o.z = f2bf((v.z - mean) * rstd * gv.z + bv.z);
    o.w = f2bf((v.w - mean) * rstd * gv.w + bv.w);
    ((ushort4*)(out + (size_t)row * E_))[tid] = o;
}

// stage one half of a tile's rows into LDS (16B/thread), source-swizzled
__device__ __forceinline__ void stage_half(const unsigned short* __restrict__ G,
                                           size_t rbase, int K, int k0,
                                           unsigned short* lds, int c) {
    const int r = c >> 3, s = c & 7;
    gload16(G + rbase + (size_t)r * K + k0 + ((s ^ (r & 7)) * 8),
            (char*)lds + c * 16);
}

// ---------------------------------------------------------------------------
// bf16 MFMA GEMM v3: C[M,N] = A[M,K] @ BT[N,K]^T (+bias)(+relu)(+res)
// BM=128, BN=256, BK=64. 512 threads = 8 waves (2M x 4N), 64x64 per wave.
// 3 LDS buffers (144 KB), depth-2 prefetch, counted vmcnt(6) in main loop
// (never 0), per-phase barrier-bracketed MFMA clusters + setprio (T3/T4/T5).
// Grids: all exact multiples of 256 blocks; XCD swizzle bijective (nwg%8==0).
// ---------------------------------------------------------------------------
template <bool BIASF, bool RELU, bool RES, bool OUTBF16>
__global__ __launch_bounds__(512) void gemm_v3(
    const unsigned short* __restrict__ A,    // [M][K] bf16
    const unsigned short* __restrict__ BT,   // [N][K] bf16
    const float* __restrict__ bias,
    const float* __restrict__ res,
    float* __restrict__ Cf,
    unsigned short* __restrict__ Cb,
    int M, int N, int K) {
    __shared__ unsigned short As[3][128 * 64];  // 3 x 16 KB
    __shared__ unsigned short Bs[3][256 * 64];  // 3 x 32 KB

    const int tid = threadIdx.x;
    const int lane = tid & 63;
    const int w = tid >> 6;             // 0..7
    const int wm = w >> 2, wn = w & 3;  // 2M x 4N
    const int lm = lane & 15;
    const int kg = lane >> 4;

    const int gx = gridDim.x;
    const int nwg = gx * gridDim.y;
    const int lin = blockIdx.y * gx + blockIdx.x;
    const int cpx = nwg >> 3;
    const int swz = (lin & 7) * cpx + (lin >> 3);
    const int rowBase = (swz / gx) * 128, colBase = (swz % gx) * 256;

    const size_t rA = (size_t)rowBase * K;
    const size_t rB = (size_t)colBase * K;

    f32x4 acc[4][4];
#pragma unroll
    for (int mt = 0; mt < 4; mt++)
#pragma unroll
        for (int nt = 0; nt < 4; nt++)
#pragma unroll
            for (int r = 0; r < 4; r++) acc[mt][nt][r] = 0.0f;

    const int nk = K >> 6;
    // prologue: stage tiles 0 and 1 (6 gloads each: A 2 + B 4 per thread)
#pragma unroll
    for (int h = 0; h < 2; h++) {
        stage_half(A, rA, K, 0, As[0], h * 512 + tid);
        stage_half(BT, rB, K, 0, Bs[0], h * 1024 + tid);
        stage_half(BT, rB, K, 0, Bs[0], h * 1024 + 512 + tid);
    }
#pragma unroll
    for (int h = 0; h < 2; h++) {
        stage_half(A, rA, K, 64, As[1], h * 512 + tid);
        stage_half(BT, rB, K, 64, Bs[1], h * 1024 + tid);
        stage_half(BT, rB, K, 64, Bs[1], h * 1024 + 512 + tid);
    }
    asm volatile("s_waitcnt vmcnt(6)" ::: "memory");  // tile 0 complete
    __builtin_amdgcn_s_barrier();
    __builtin_amdgcn_sched_barrier(0);

    for (int t = 0; t < nk; ++t) {
        const int cur = t % 3;
        const int nx2 = (t + 2) % 3;
        const bool doStage = (t + 2 < nk);
#pragma unroll
        for (int ks = 0; ks < 2; ++ks) {
            // ds_read 8 frags for this k-step
            bf16x8 af[4], bfr[4];
#pragma unroll
            for (int mt = 0; mt < 4; mt++) {
                const int r = wm * 64 + mt * 16 + lm;
                af[mt] = *(const bf16x8*)(As[cur] + r * 64 +
                                          (((ks * 4 + kg) ^ (r & 7)) * 8));
            }
#pragma unroll
            for (int nt = 0; nt < 4; nt++) {
                const int r = wn * 64 + nt * 16 + lm;
                bfr[nt] = *(const bf16x8*)(Bs[cur] + r * 64 +
                                           (((ks * 4 + kg) ^ (r & 7)) * 8));
            }
            // issue half of tile t+2's staging (3 gloads)
            if (doStage) {
                stage_half(A, rA, K, (t + 2) * 64, As[nx2], ks * 512 + tid);
                stage_half(BT, rB, K, (t + 2) * 64, Bs[nx2], ks * 1024 + tid);
                stage_half(BT, rB, K, (t + 2) * 64, Bs[nx2], ks * 1024 + 512 + tid);
            }
            __builtin_amdgcn_s_barrier();
            __builtin_amdgcn_sched_barrier(0);
            __builtin_amdgcn_s_setprio(1);
#pragma unroll
            for (int mt = 0; mt < 4; mt++)
#pragma unroll
                for (int nt = 0; nt < 4; nt++)
                    acc[mt][nt] = __builtin_amdgcn_mfma_f32_16x16x32_bf16(
                        af[mt], bfr[nt], acc[mt][nt], 0, 0, 0);
            __builtin_amdgcn_s_setprio(0);
            if (ks == 0) {
                __builtin_amdgcn_s_barrier();
                __builtin_amdgcn_sched_barrier(0);
            }
        }
        // end of K-tile: ensure tile t+1's staging (issued at iter t-1) done
        if (t + 2 < nk) {
            asm volatile("s_waitcnt vmcnt(6)" ::: "memory");
        } else if (t + 1 < nk) {
            asm volatile("s_waitcnt vmcnt(0)" ::: "memory");
        }
        __builtin_amdgcn_sched_barrier(0);
        __builtin_amdgcn_s_barrier();
        __builtin_amdgcn_sched_barrier(0);
    }

    // epilogue: C/D layout col=lane&15, row=(lane>>4)*4+reg
#pragma unroll
    for (int mt = 0; mt < 4; mt++) {
#pragma unroll
        for (int nt = 0; nt < 4; nt++) {
            const int cg = colBase + wn * 64 + nt * 16 + lm;
#pragma unroll
            for (int r = 0; r < 4; r++) {
                const int rg = rowBase + wm * 64 + mt * 16 + kg * 4 + r;
                float v = acc[mt][nt][r];
                if (BIASF) v += bias[cg];
                if (RELU) v = fmaxf(v, 0.0f);
                if (RES) v += res[(size_t)rg * N + cg];
                if (OUTBF16) Cb[(size_t)rg * N + cg] = f2bf(v);
                else Cf[(size_t)rg * N + cg] = v;
            }
        }
    }
}

// ---------------------------------------------------------------------------
// bf16 MFMA flash attention v3 (causal). Same math as v2 (verified), now with
// K/V LDS double-buffer and ONE raw barrier per tile (lgkmcnt-only: the
// early-issued next-tile global loads stay in flight across the barrier).
// Safety: a wave writing buf[(t+1)&1] at iter t+1 has passed barrier(t),
// which all waves reach only after compute(t-1) (last readers) completed
// with ds_read data consumed by MFMAs.
// ---------------------------------------------------------------------------
__global__ __launch_bounds__(256) void attn_mfma3(const unsigned short* __restrict__ qkv,
                                                  unsigned short* __restrict__ out) {
    __shared__ unsigned short Ks[2][64 * 64];  // 2 x 8 KB, XOR-swizzled
    __shared__ unsigned short Vt[2][64 * 72];  // 2 x 9 KB, [d][kv] pitch 72

    const int tid = threadIdx.x;
    const int lane = tid & 63;
    const int w = tid >> 6;
    const int lm = lane & 15;
    const int kg = lane >> 4;
    const int qt = 15 - blockIdx.x;      // 0..15, descending dispatch
    const int bh = blockIdx.y;           // 0..63
    const int b = bh >> 4, h = bh & 15;
    const int bT = b * T_;
    const int q0w = qt * 128 + w * 32;
    const float K1 = 0.18033688011f;     // 0.125 * log2(e)

    // Q fragments [qg][d-chunk], hoisted
    bf16x8 qf[2][2];
#pragma unroll
    for (int qg = 0; qg < 2; qg++) {
        const size_t qo = (size_t)(bT + q0w + qg * 16 + lm) * QKV3_ + h * HS_;
#pragma unroll
        for (int dc = 0; dc < 2; dc++)
            qf[qg][dc] = *(const bf16x8*)(qkv + qo + dc * 32 + kg * 8);
    }

    f32x4 o[2][4];
#pragma unroll
    for (int qg = 0; qg < 2; qg++)
#pragma unroll
        for (int dt = 0; dt < 4; dt++)
#pragma unroll
            for (int r = 0; r < 4; r++) o[qg][dt][r] = 0.0f;
    float m2[2] = {-INFINITY, -INFINITY};
    float l[2] = {0.0f, 0.0f};

    // staging assignment
    const int rK = tid >> 3, chK = tid & 7;        // K: rows rK, rK+32; chunk chK
    const int sK = (chK ^ (rK & 7)) * 8;           // swizzled LDS slot (elems)
    const int rp = tid >> 3, chV = tid & 7;        // V: row pair 2rp,2rp+1
    const int vws = (2 * rp) ^ (chV << 2);         // swizzled kv-slot for V writes

    const size_t hK = E_ + h * HS_;
    const size_t hV = 2 * E_ + h * HS_;
    bf16x8 kA, kB, vA, vB;

#define LOADT(kvb)                                                                          \
    do {                                                                                    \
        kA = *(const bf16x8*)(qkv + (size_t)(bT + (kvb) + rK) * QKV3_ + hK + chK * 8);      \
        kB = *(const bf16x8*)(qkv + (size_t)(bT + (kvb) + rK + 32) * QKV3_ + hK + chK * 8); \
        vA = *(const bf16x8*)(qkv + (size_t)(bT + (kvb) + 2 * rp) * QKV3_ + hV + chV * 8);  \
        vB = *(const bf16x8*)(qkv + (size_t)(bT + (kvb) + 2 * rp + 1) * QKV3_ + hV + chV * 8); \
    } while (0)

    const int nt = 2 * (qt + 1);
    LOADT(0);
    for (int t = 0; t < nt; t++) {
        const int kvbase = t * 64;
        const int cb = t & 1;
        // write tile t (in regs) into buf cb
        *(bf16x8*)(Ks[cb] + rK * 64 + sK) = kA;
        *(bf16x8*)(Ks[cb] + (rK + 32) * 64 + sK) = kB;
#pragma unroll
        for (int i = 0; i < 8; i++) {
            const unsigned int pv = (unsigned int)(unsigned short)vA[i] |
                                    ((unsigned int)(unsigned short)vB[i] << 16);
            *(unsigned int*)(Vt[cb] + (chV * 8 + i) * 72 + vws) = pv;
        }
        if (t + 1 < nt) LOADT((t + 1) * 64);  // early-issue next tile (T14)
        asm volatile("s_waitcnt lgkmcnt(0)" ::: "memory");  // LDS writes visible
        __builtin_amdgcn_s_barrier();
        __builtin_amdgcn_sched_barrier(0);
        if (kvbase > q0w + 31) continue;  // wave fully masked (uniform)

        // K fragments (conflict-free swizzled b128)
        bf16x8 af[4][2];
#pragma unroll
        for (int g = 0; g < 4; g++)
#pragma unroll
            for (int dc = 0; dc < 2; dc++)
                af[g][dc] = *(const bf16x8*)(Ks[cb] + (g * 16 + lm) * 64 +
                                             (((dc * 4 + kg) ^ (lm & 7)) * 8));

        bf16x8 pa[2][2];
#pragma unroll
        for (int qg = 0; qg < 2; qg++) {
            f32x4 z = {0.0f, 0.0f, 0.0f, 0.0f};
            f32x4 s[4];
#pragma unroll
            for (int g = 0; g < 4; g++) {
                s[g] = __builtin_amdgcn_mfma_f32_16x16x32_bf16(af[g][0], qf[qg][0], z, 0, 0, 0);
                s[g] = __builtin_amdgcn_mfma_f32_16x16x32_bf16(af[g][1], qf[qg][1], s[g], 0, 0, 0);
            }
            const int qrow = q0w + qg * 16 + lm;
            float sv[16];
#pragma unroll
            for (int g = 0; g < 4; g++)
#pragma unroll
                for (int r = 0; r < 4; r++) sv[g * 4 + r] = s[g][r];
            if (kvbase + 63 > q0w + qg * 16) {  // diagonal tile: causal mask
#pragma unroll
                for (int g = 0; g < 4; g++)
#pragma unroll
                    for (int r = 0; r < 4; r++) {
                        const int kv = kvbase + g * 16 + kg * 4 + r;
                        if (kv > qrow) sv[g * 4 + r] = -INFINITY;
                    }
            }
            // depth-4 max tree
            const float mx = fmaxf(
                fmaxf(fmaxf(fmaxf(sv[0], sv[1]), fmaxf(sv[2], sv[3])),
                      fmaxf(fmaxf(sv[4], sv[5]), fmaxf(sv[6], sv[7]))),
                fmaxf(fmaxf(fmaxf(sv[8], sv[9]), fmaxf(sv[10], sv[11])),
                      fmaxf(fmaxf(sv[12], sv[13]), fmaxf(sv[14], sv[15]))));
            float mxw = fmaxf(mx, __shfl_xor(mx, 16));
            mxw = fmaxf(mxw, __shfl_xor(mxw, 32));
            const float mx2 = mxw * K1;
            // defer-max: rescale only when max grew beyond threshold (uniform)
            if (!__all(m2[qg] > -1e30f && mx2 <= m2[qg] + 11.5f)) {
                const float m2new = fmaxf(m2[qg], mx2);
                const float alpha = exp2f(m2[qg] - m2new);
#pragma unroll
                for (int r = 0; r < 4; r++) {
                    const float ar = __shfl(alpha, kg * 4 + r);
#pragma unroll
                    for (int dt = 0; dt < 4; dt++) o[qg][dt][r] *= ar;
                }
                l[qg] *= alpha;
                m2[qg] = m2new;
            }
            float p[16];
#pragma unroll
            for (int j = 0; j < 16; j++) p[j] = exp2f(fmaf(sv[j], K1, -m2[qg]));
            // depth-4 sum tree
            float ls = (((p[0] + p[1]) + (p[2] + p[3])) + ((p[4] + p[5]) + (p[6] + p[7]))) +
                       (((p[8] + p[9]) + (p[10] + p[11])) + ((p[12] + p[13]) + (p[14] + p[15])));
            ls += __shfl_xor(ls, 16);
            ls += __shfl_xor(ls, 32);
            l[qg] += ls;
#pragma unroll
            for (int j = 0; j < 8; j++) {
                ((unsigned short*)&pa[qg][0])[j] = f2bf(p[j]);
                ((unsigned short*)&pa[qg][1])[j] = f2bf(p[8 + j]);
            }
        }

        // PV: vf fragments (2x b64 each, de-swizzled via row-octet XOR), shared
        // by both q-groups
#pragma unroll
        for (int dt = 0; dt < 4; dt++) {
            const int drow = dt * 16 + lm;
            const unsigned short* vrow = Vt[cb] + drow * 72;
            const int xo = (kg * 4) ^ (((drow >> 3) & 7) << 2);
#pragma unroll
            for (int c = 0; c < 2; c++) {
                const bf16x4 lo = *(const bf16x4*)(vrow + c * 32 + xo);
                const bf16x4 hi = *(const bf16x4*)(vrow + c * 32 + (xo ^ 16));
                const bf16x8 vf = __builtin_shufflevector(lo, hi, 0, 1, 2, 3, 4, 5, 6, 7);
                o[0][dt] = __builtin_amdgcn_mfma_f32_16x16x32_bf16(pa[0][c], vf, o[0][dt], 0, 0, 0);
                o[1][dt] = __builtin_amdgcn_mfma_f32_16x16x32_bf16(pa[1][c], vf, o[1][dt], 0, 0, 0);
            }
        }
    }
#undef LOADT

    // epilogue: out row q = kg*4+r (per qg), col d = dt*16+lm
#pragma unroll
    for (int qg = 0; qg < 2; qg++)
#pragma unroll
        for (int r = 0; r < 4; r++) {
            const float li = 1.0f / __shfl(l[qg], kg * 4 + r);
            const size_t ro = (size_t)(bT + q0w + qg * 16 + kg * 4 + r) * E_ + h * HS_;
#pragma unroll
            for (int dt = 0; dt < 4; dt++)
                out[ro + dt * 16 + lm] = f2bf(o[qg][dt][r] * li);
        }
}

// ---------------------------------------------------------------------------
// Workspace layout (bytes): peak ~120 MB.
// ---------------------------------------------------------------------------
extern "C" void kernel_launch(void* const* d_in, const int* in_sizes, int n_in,
                              void* d_out, int out_size, void* d_ws, size_t ws_size,
                              hipStream_t stream) {
    const float* x           = (const float*)d_in[0];
    const float* qkv_w       = (const float*)d_in[1];
    const float* attn_proj_w = (const float*)d_in[2];
    const float* attn_proj_b = (const float*)d_in[3];
    const float* ln1_g       = (const float*)d_in[4];
    const float* ln1_b       = (const float*)d_in[5];
    const float* ln2_g       = (const float*)d_in[6];
    const float* ln2_b       = (const float*)d_in[7];
    const float* ff_w1       = (const float*)d_in[8];
    const float* ff_b1       = (const float*)d_in[9];
    const float* ff_w2       = (const float*)d_in[10];
    const float* ff_b2       = (const float*)d_in[11];
    float* out = (float*)d_out;
    char* wsb = (char*)d_ws;

    unsigned short* wqkvT  = (unsigned short*)(wsb + 0);
    unsigned short* wprojT = (unsigned short*)(wsb + 6291456);
    unsigned short* wff1T  = (unsigned short*)(wsb + 8388608);
    unsigned short* wff2T  = (unsigned short*)(wsb + 16777216);
    unsigned short* hbuf   = (unsigned short*)(wsb + 25165824);
    unsigned short* attnb  = (unsigned short*)(wsb + 41943040);
    unsigned short* qkvb   = (unsigned short*)(wsb + 58720256);
    unsigned short* ff1b   = qkvb;  // reuse (qkv dead after attention)

    // weight transposes (W[K][N] -> WT[N][K] bf16)
    wT_bf16<<<dim3(QKV3_ / 32, E_ / 32), 256, 0, stream>>>(qkv_w, wqkvT, E_, QKV3_);
    wT_bf16<<<dim3(E_ / 32, E_ / 32), 256, 0, stream>>>(attn_proj_w, wprojT, E_, E_);
    wT_bf16<<<dim3(FF_ / 32, E_ / 32), 256, 0, stream>>>(ff_w1, wff1T, E_, FF_);
    wT_bf16<<<dim3(E_ / 32, FF_ / 32), 256, 0, stream>>>(ff_w2, wff2T, FF_, E_);

    // 1. h = LN1(x) -> bf16
    ln_bf16<<<M_, 256, 0, stream>>>(x, ln1_g, ln1_b, hbuf);
    // 2. qkv = h @ qkv_w -> bf16   (grid 12x64 = 768 blocks)
    gemm_v3<false, false, false, true><<<dim3(QKV3_ / 256, M_ / 128), 512, 0, stream>>>(
        hbuf, wqkvT, nullptr, nullptr, nullptr, qkvb, M_, QKV3_, E_);
    // 3. attn = causal_flash(qkv) -> bf16
    attn_mfma3<<<dim3(T_ / 128, B_ * H_), 256, 0, stream>>>(qkvb, attnb);
    // 4. x1 = x + attn @ proj_w + proj_b -> d_out (fp32)  (grid 4x64 = 256)
    gemm_v3<true, false, true, false><<<dim3(E_ / 256, M_ / 128), 512, 0, stream>>>(
        attnb, wprojT, attn_proj_b, x, out, nullptr, M_, E_, E_);
    // 5. h2 = LN2(x1) -> bf16
    ln_bf16<<<M_, 256, 0, stream>>>(out, ln2_g, ln2_b, hbuf);
    // 6. ff = relu(h2 @ ff_w1 + b1) -> bf16   (grid 16x64 = 1024)
    gemm_v3<true, true, false, true><<<dim3(FF_ / 256, M_ / 128), 512, 0, stream>>>(
        hbuf, wff1T, ff_b1, nullptr, nullptr, ff1b, M_, FF_, E_);
    // 7. out = x1 + ff @ ff_w2 + b2 -> d_out (fp32, in-place residual) (4x64)
    gemm_v3<true, false, true, false><<<dim3(E_ / 256, M_ / 128), 512, 0, stream>>>(
        ff1b, wff2T, ff_b2, out, out, nullptr, M_, E_, FF_);
    (void)ws_size; (void)in_sizes; (void)n_in; (void)out_size;
}